// Round 8
// baseline (72.351 us; speedup 1.0000x reference)
//
#include <hip/hip_runtime.h>

#define N_WORD 32000
#define DIM    300
#define BQ     32
#define WW     8
#define NNEG   2392
#define PERB   (WW*NNEG)     // 19136
#define NTOT   (BQ*PERB)     // 612352
#define NC     4             // k-chunks: dims [0,80) [80,160) [160,240) [240,300)
#define KC     96            // padded chunk length (3 x 32)
#define LR     104           // LDS row stride in bf16 (208 B: 13*16 -> bank spread)
#define NBLK3  1024
#define FSCALE 268435456.0   // 2^28 fixed-point scale for deterministic sum

typedef __attribute__((ext_vector_type(8))) short short8;   // 8 bf16 = 4 VGPR
typedef __attribute__((ext_vector_type(4))) float f32x4;

__device__ __forceinline__ unsigned f2b2(float lo, float hi) {
  unsigned ul = __builtin_bit_cast(unsigned, lo);
  unsigned uh = __builtin_bit_cast(unsigned, hi);
  ul = (ul + 0x7FFF + ((ul >> 16) & 1)) >> 16;
  uh = (uh + 0x7FFF + ((uh >> 16) & 1));
  return (ul & 0xFFFFu) | (uh & 0xFFFF0000u);
}
__device__ __forceinline__ unsigned short f2b(float f) {
  unsigned u = __builtin_bit_cast(unsigned, f);
  return (unsigned short)((u + 0x7FFF + ((u >> 16) & 1)) >> 16);
}

// ---- kernel 1: blocks 0..31 build tgt bags as [c][b][96] bf16 (zero-pad);
//      blocks 32..159 zero the 4 MB S table; block 32 zeros acc/cnt. ----
__global__ __launch_bounds__(256) void prep_kernel(
    const float* __restrict__ char_emb, const float* __restrict__ compo_emb,
    const int* __restrict__ chars, const int* __restrict__ compos,
    unsigned short* __restrict__ tgt_bf, float* __restrict__ S,
    unsigned long long* __restrict__ acc, int* __restrict__ cnt) {
  if (blockIdx.x < BQ) {
    int b = blockIdx.x;
    for (int idx = threadIdx.x; idx < NC*KC; idx += 256) {
      int c = idx / KC, kk = idx - c*KC;
      int d = c*80 + kk;
      float a = 0.f;
      if (kk < 80 && d < DIM) {
        #pragma unroll
        for (int j = 0; j < 4; ++j) {
          int ch = chars[b*4 + j];
          if (ch != 1) a += char_emb[(size_t)ch*DIM + d];
        }
        #pragma unroll
        for (int j = 0; j < 8; ++j) {
          int ch = compos[b*8 + j];
          if (ch != 1) a += compo_emb[(size_t)ch*DIM + d];
        }
      }
      tgt_bf[(c*BQ + b)*KC + kk] = (kk < 80 && d < DIM) ? f2b(a) : (unsigned short)0;
    }
  } else {
    if (blockIdx.x == BQ && threadIdx.x == 0) { *acc = 0ULL; *cnt = 0; }
    int nb = gridDim.x - BQ;
    int4* s4 = (int4*)S;
    const int tot4 = BQ*N_WORD/4;   // 256000
    for (int i = (blockIdx.x - BQ)*256 + threadIdx.x; i < tot4; i += nb*256)
      s4[i] = make_int4(0, 0, 0, 0);
  }
}

// ---- kernel 2: K-split MFMA GEMM; partial S via f32 atomicAdd ----
// grid (500, 4): 64 v-rows x k-chunk c. 20 KB LDS -> 4+ blocks/CU resident;
// 2000 blocks interleave staging/compute phases so HBM stays fed.
__global__ __launch_bounds__(256, 4) void s_gemm_kernel(
    const float* __restrict__ w, const unsigned short* __restrict__ tgt_bf,
    float* __restrict__ S) {
  __shared__ unsigned short wt[64][LR];   // 13312 B
  __shared__ unsigned short tt[BQ][LR];   //  6656 B
  int tid = threadIdx.x, wv = tid >> 6, lane = tid & 63;
  int c = blockIdx.y;
  int vbase = blockIdx.x * 64;
  int WC = (c == 3) ? 60 : 80;            // valid dims in this chunk

  // stage word tile: rows contiguous-coalesced float4 (chunk start 320 B-aligned)
  const float* src = w + (size_t)vbase*DIM + c*80;
  if (c < 3) {
    const int F = 20;                     // float4 per row
    for (int idx = tid; idx < 64*F; idx += 256) {
      int row = idx / F, col = idx - row*F;
      float4 x = *(const float4*)(src + (size_t)row*DIM + col*4);
      uint2 p = { f2b2(x.x, x.y), f2b2(x.z, x.w) };
      *(uint2*)&wt[row][col*4] = p;
    }
  } else {
    const int F = 15;
    for (int idx = tid; idx < 64*F; idx += 256) {
      int row = idx / F, col = idx - row*F;
      float4 x = *(const float4*)(src + (size_t)row*DIM + col*4);
      uint2 p = { f2b2(x.x, x.y), f2b2(x.z, x.w) };
      *(uint2*)&wt[row][col*4] = p;
    }
  }
  {   // zero-pad kk in [WC,96)
    int npad2 = (KC - WC) >> 1;           // u32 slots per row (8 or 18)
    for (int k2 = tid; k2 < 64*npad2; k2 += 256) {
      int row = k2 / npad2, j = k2 - row*npad2;
      *(unsigned*)&wt[row][WC + 2*j] = 0u;
    }
  }
  // stage tgt tile for chunk c: 32x96 bf16 = 384 uint4 (pads pre-baked)
  {
    const uint4* tsrc = (const uint4*)(tgt_bf + (size_t)c*BQ*KC);
    for (int idx = tid; idx < BQ*KC/8; idx += 256) {   // 384
      int p = idx*8, row = p / KC, col = p - row*KC;
      *(uint4*)&tt[row][col] = tsrc[idx];
    }
  }
  __syncthreads();

  // A and B fragments use the same lane->(row,k) formula: k-permutation cancels.
  int ln = lane & 15, g = lane >> 4;
  f32x4 acc0 = {0.f,0.f,0.f,0.f}, acc1 = {0.f,0.f,0.f,0.f};
  #pragma unroll
  for (int ks = 0; ks < KC/32; ++ks) {
    short8 bf = *(const short8*)&wt[wv*16 + ln][ks*32 + g*8];
    short8 a0 = *(const short8*)&tt[ln][ks*32 + g*8];
    short8 a1 = *(const short8*)&tt[16 + ln][ks*32 + g*8];
    acc0 = __builtin_amdgcn_mfma_f32_16x16x32_bf16(a0, bf, acc0, 0, 0, 0);
    acc1 = __builtin_amdgcn_mfma_f32_16x16x32_bf16(a1, bf, acc1, 0, 0, 0);
  }

  // D: col = lane&15 (v), row = (lane>>4)*4 + reg (b)  [m89-verified]
  int v = vbase + wv*16 + ln;
  #pragma unroll
  for (int r = 0; r < 4; ++r) {
    int b0 = g*4 + r;
    atomicAdd(&S[(size_t)b0*N_WORD + v],        acc0[r]);
    atomicAdd(&S[(size_t)(b0 + 16)*N_WORD + v], acc1[r]);
  }
}

// ---- kernel 3: gather S at noise/ctx indices, sum log-sigmoid; fused final ----
__global__ __launch_bounds__(256) void loss_kernel(
    const float* __restrict__ S, const int* __restrict__ noise,
    const int* __restrict__ ctx, unsigned long long* __restrict__ acc,
    int* __restrict__ cnt, float* __restrict__ out) {
  float a = 0.f;
  for (int i = blockIdx.x*256 + threadIdx.x; i < NTOT; i += 256*NBLK3) {
    int b = i / PERB;                 // constant divisor -> magic mul
    int idx = noise[i];
    float s = S[(size_t)b*N_WORD + idx];
    a += __logf(1.f/(1.f + __expf(s)) + 1e-32f);
  }
  if (blockIdx.x == 0) {
    int i = threadIdx.x;              // i = b*8 + w covers all 256 (b,w)
    int c = ctx[i];
    float s = (c == 1) ? 0.f : S[(size_t)(i >> 3)*N_WORD + c];
    a += __logf(1.f/(1.f + __expf(-s)));
  }
  #pragma unroll
  for (int off = 32; off > 0; off >>= 1) a += __shfl_down(a, off);
  __shared__ float wsum[4];
  int lane = threadIdx.x & 63, wid = threadIdx.x >> 6;
  if (lane == 0) wsum[wid] = a;
  __syncthreads();
  if (threadIdx.x == 0) {
    float partial = wsum[0] + wsum[1] + wsum[2] + wsum[3];
    unsigned long long enc =
        (unsigned long long)(long long)llrintf(partial * (float)FSCALE);
    atomicAdd(acc, enc);
    __threadfence();
    int old = atomicAdd(cnt, 1);
    if (old == NBLK3 - 1) {           // last block: all adds visible
      long long tot = (long long)atomicAdd(acc, 0ULL);
      out[0] = (float)(-((double)tot / FSCALE) / (double)BQ);
    }
  }
}

extern "C" void kernel_launch(void* const* d_in, const int* in_sizes, int n_in,
                              void* d_out, int out_size, void* d_ws, size_t ws_size,
                              hipStream_t stream) {
  const float* word_emb  = (const float*)d_in[0];   // [32000,300]
  const float* char_emb  = (const float*)d_in[1];   // [8000,300]
  const float* compo_emb = (const float*)d_in[2];   // [1000,300]
  const int*   chars     = (const int*)d_in[3];     // [32,4]
  const int*   compos    = (const int*)d_in[4];     // [32,8]
  const int*   ctx       = (const int*)d_in[5];     // [32,8]
  const int*   noise     = (const int*)d_in[6];     // [32,8,2392]
  float* out = (float*)d_out;

  char* ws = (char*)d_ws;
  unsigned short*     tgt_bf = (unsigned short*)(ws);           // 24576 B
  float*              S      = (float*)(ws + 24576);            // 4,096,000 B
  unsigned long long* acc    = (unsigned long long*)(ws + 24576 + 4096000);
  int*                cnt    = (int*)(ws + 24576 + 4096000 + 8);

  prep_kernel<<<160, 256, 0, stream>>>(char_emb, compo_emb, chars, compos,
                                       tgt_bf, S, acc, cnt);
  s_gemm_kernel<<<dim3(N_WORD/64, NC), 256, 0, stream>>>(word_emb, tgt_bf, S);
  loss_kernel<<<NBLK3, 256, 0, stream>>>(S, noise, ctx, acc, cnt, out);
}

// Round 9
// 59.198 us; speedup vs baseline: 1.2222x; 1.2222x over previous
//
#include <hip/hip_runtime.h>

#define N_WORD 32000
#define DIM    300
#define KP     320           // A-side K padded to 10 x 32 (zeros baked by prep)
#define BQ     32
#define WW     8
#define NNEG   2392
#define PERB   (WW*NNEG)     // 19136
#define NTOT   (BQ*PERB)     // 612352
#define VB     32            // word rows per GEMM block
#define NGEMB  (N_WORD/VB)   // 1000
#define NBLK3  1024
#define FSCALE 268435456.0   // 2^28 fixed-point scale for deterministic sum

typedef __attribute__((ext_vector_type(8))) short short8;   // 8 bf16 = 4 VGPR
typedef __attribute__((ext_vector_type(4))) float f32x4;

__device__ __forceinline__ unsigned f2b2(float lo, float hi) {
  // pack two floats to two RNE-rounded bf16 in one u32
  unsigned ul = __builtin_bit_cast(unsigned, lo);
  unsigned uh = __builtin_bit_cast(unsigned, hi);
  ul = (ul + 0x7FFF + ((ul >> 16) & 1)) >> 16;
  uh = (uh + 0x7FFF + ((uh >> 16) & 1));
  return (ul & 0xFFFFu) | (uh & 0xFFFF0000u);
}
__device__ __forceinline__ unsigned short f2b(float f) {
  unsigned u = __builtin_bit_cast(unsigned, f);
  return (unsigned short)((u + 0x7FFF + ((u >> 16) & 1)) >> 16);
}

__device__ __forceinline__ void gload_lds16(const float* g, float* l) {
  // async global->LDS DMA, 16 B/lane; LDS dest = wave-uniform base + lane*16
  __builtin_amdgcn_global_load_lds(
      (const __attribute__((address_space(1))) void*)g,
      (__attribute__((address_space(3))) void*)l, 16, 0, 0);
}

// ---- kernel 1: tgt bags -> bf16-packed [32][320] (zero k-pad); zero acc/cnt ----
__global__ __launch_bounds__(256) void prep_kernel(
    const float* __restrict__ char_emb, const float* __restrict__ compo_emb,
    const int* __restrict__ chars, const int* __restrict__ compos,
    unsigned short* __restrict__ tgt_bf,
    unsigned long long* __restrict__ acc, int* __restrict__ cnt) {
  if (blockIdx.x == 0 && threadIdx.x == 0) { *acc = 0ULL; *cnt = 0; }
  int b = blockIdx.x;
  for (int d = threadIdx.x; d < KP; d += 256) {
    float a = 0.f;
    if (d < DIM) {
      #pragma unroll
      for (int j = 0; j < 4; ++j) {
        int c = chars[b*4 + j];
        if (c != 1) a += char_emb[(size_t)c*DIM + d];
      }
      #pragma unroll
      for (int j = 0; j < 8; ++j) {
        int c = compos[b*8 + j];
        if (c != 1) a += compo_emb[(size_t)c*DIM + d];
      }
    }
    tgt_bf[b*KP + d] = (d < DIM) ? f2b(a) : (unsigned short)0;
  }
}

// ---- kernel 2: MFMA GEMM with async global_load_lds staging ----
// 1000 blocks x 256 thr (4 waves). Block stages 32 contiguous word rows
// (38.4 KB f32, LINEAR layout -- required by global_load_lds) via 10 async
// DMAs/thread, all in flight until the barrier's vmcnt(0). f32->bf16 convert
// happens in the MFMA phase. Wave wv owns (v-tile wv&1, b-tile wv>>1).
__global__ __launch_bounds__(256) void s_gemm_kernel(
    const float* __restrict__ w, const unsigned short* __restrict__ tgt_bf,
    float* __restrict__ S) {
  __shared__ float wt[VB*DIM + 20];   // 9620 f32 = 38480 B; +20 tail pad
  int tid = threadIdx.x, wv = tid >> 6, lane = tid & 63;
  int vbase = blockIdx.x * VB;
  const float* src = w + (size_t)vbase*DIM;   // 1200-B aligned

  #pragma unroll
  for (int r = 0; r < 9; ++r)        // 9*256 = 2304 of 2400 float4
    gload_lds16(src + (size_t)(r*256 + tid)*4, wt + (r*256 + wv*64)*4);
  if (tid < 96)                       // tail: exec-masked in wave 1
    gload_lds16(src + (size_t)(2304 + tid)*4, wt + (2304 + wv*64)*4);
  if (tid < 20) wt[VB*DIM + tid] = 0.f;   // keep tail pad finite (NaN x 0 = NaN)
  __syncthreads();                    // drains vmcnt(0): all DMAs landed

  int ln = lane & 15, g = lane >> 4;
  int vt = wv & 1, bt = wv >> 1;
  const float* bp = wt + (vt*16 + ln)*DIM;
  const unsigned short* ap = tgt_bf + (size_t)(bt*16 + ln)*KP;
  f32x4 acc = {0.f, 0.f, 0.f, 0.f};
  #pragma unroll
  for (int kb = 0; kb < KP/32; ++kb) {
    int k0 = kb*32 + g*8;
    // rows 0..30: k>=300 aliases next row (finite, A=0 there); row 31: tail pad
    float4 b0 = *(const float4*)(bp + k0);
    float4 b1 = *(const float4*)(bp + k0 + 4);
    short8 bf;
    unsigned* bu = (unsigned*)&bf;
    bu[0] = f2b2(b0.x, b0.y); bu[1] = f2b2(b0.z, b0.w);
    bu[2] = f2b2(b1.x, b1.y); bu[3] = f2b2(b1.z, b1.w);
    short8 a = *(const short8*)(ap + kb*32 + g*8);
    acc = __builtin_amdgcn_mfma_f32_16x16x32_bf16(a, bf, acc, 0, 0, 0);
  }

  // D: col = lane&15 (v), row = (lane>>4)*4 + reg (b)  [m89-verified]
  int v = vbase + vt*16 + ln;
  #pragma unroll
  for (int r = 0; r < 4; ++r) {
    int b0 = bt*16 + g*4 + r;
    S[(size_t)b0*N_WORD + v] = acc[r];
  }
}

// ---- kernel 3: gather S at noise/ctx indices, sum log-sigmoid; fused final ----
// Deterministic cross-block sum: fixed-point int64 atomics (order-invariant).
__global__ __launch_bounds__(256) void loss_kernel(
    const float* __restrict__ S, const int* __restrict__ noise,
    const int* __restrict__ ctx, unsigned long long* __restrict__ acc,
    int* __restrict__ cnt, float* __restrict__ out) {
  float a = 0.f;
  for (int i = blockIdx.x*256 + threadIdx.x; i < NTOT; i += 256*NBLK3) {
    int b = i / PERB;                 // constant divisor -> magic mul
    int idx = noise[i];
    float s = S[(size_t)b*N_WORD + idx];
    a += __logf(1.f/(1.f + __expf(s)) + 1e-32f);
  }
  if (blockIdx.x == 0) {
    int i = threadIdx.x;              // i = b*8 + w covers all 256 (b,w)
    int c = ctx[i];
    float s = (c == 1) ? 0.f : S[(size_t)(i >> 3)*N_WORD + c];
    a += __logf(1.f/(1.f + __expf(-s)));
  }
  #pragma unroll
  for (int off = 32; off > 0; off >>= 1) a += __shfl_down(a, off);
  __shared__ float wsum[4];
  int lane = threadIdx.x & 63, wid = threadIdx.x >> 6;
  if (lane == 0) wsum[wid] = a;
  __syncthreads();
  if (threadIdx.x == 0) {
    float partial = wsum[0] + wsum[1] + wsum[2] + wsum[3];
    unsigned long long enc =
        (unsigned long long)(long long)llrintf(partial * (float)FSCALE);
    atomicAdd(acc, enc);
    __threadfence();
    int old = atomicAdd(cnt, 1);
    if (old == NBLK3 - 1) {           // last block: all adds visible
      long long tot = (long long)atomicAdd(acc, 0ULL);
      out[0] = (float)(-((double)tot / FSCALE) / (double)BQ);
    }
  }
}

extern "C" void kernel_launch(void* const* d_in, const int* in_sizes, int n_in,
                              void* d_out, int out_size, void* d_ws, size_t ws_size,
                              hipStream_t stream) {
  const float* word_emb  = (const float*)d_in[0];   // [32000,300]
  const float* char_emb  = (const float*)d_in[1];   // [8000,300]
  const float* compo_emb = (const float*)d_in[2];   // [1000,300]
  const int*   chars     = (const int*)d_in[3];     // [32,4]
  const int*   compos    = (const int*)d_in[4];     // [32,8]
  const int*   ctx       = (const int*)d_in[5];     // [32,8]
  const int*   noise     = (const int*)d_in[6];     // [32,8,2392]
  float* out = (float*)d_out;

  char* ws = (char*)d_ws;
  unsigned short*     tgt_bf = (unsigned short*)(ws);            // 20480 B
  float*              S      = (float*)(ws + 20480);             // 4,096,000 B
  unsigned long long* acc    = (unsigned long long*)(ws + 20480 + 4096000);
  int*                cnt    = (int*)(ws + 20480 + 4096000 + 8);

  prep_kernel<<<BQ, 256, 0, stream>>>(char_emb, compo_emb, chars, compos,
                                      tgt_bf, acc, cnt);
  s_gemm_kernel<<<NGEMB, 256, 0, stream>>>(word_emb, tgt_bf, S);
  loss_kernel<<<NBLK3, 256, 0, stream>>>(S, noise, ctx, acc, cnt, out);
}